// Round 9
// baseline (998.825 us; speedup 1.0000x reference)
//
#include <hip/hip_runtime.h>
#include <hip/hip_bf16.h>
#include <math.h>

#define MUL 8
#define NCOL 144   // 16*(1+3+5)
#define EREC 56    // per-edge record: t0[16] t1[16] t2[16] y1[3] y2[5]
#define SPAD 60    // LDS stage stride in floats (padded, 16B-aligned)

__device__ __forceinline__ float silu_f(float x) { return x / (1.0f + __expf(-x)); }

// ---------------- node MLP -> Ai[N][8] ----------------
__global__ void node_mlp_kernel(const int* __restrict__ A,
                                const float* __restrict__ emb_table,
                                const float* __restrict__ w1,
                                const float* __restrict__ b1,
                                const float* __restrict__ w2,
                                const float* __restrict__ b2,
                                float* __restrict__ Ai, int N) {
    __shared__ float s_w1[16 * 64];
    __shared__ float s_w2[64 * MUL];
    __shared__ float s_b1[64];
    __shared__ float s_b2[MUL];
    __shared__ float s_emb[10 * 16];
    for (int i = threadIdx.x; i < 16 * 64; i += blockDim.x) s_w1[i] = w1[i];
    for (int i = threadIdx.x; i < 64 * MUL; i += blockDim.x) s_w2[i] = w2[i];
    for (int i = threadIdx.x; i < 64; i += blockDim.x) s_b1[i] = b1[i];
    for (int i = threadIdx.x; i < MUL; i += blockDim.x) s_b2[i] = b2[i];
    for (int i = threadIdx.x; i < 160; i += blockDim.x) s_emb[i] = emb_table[i];
    __syncthreads();

    int n = blockIdx.x * blockDim.x + threadIdx.x;
    if (n >= N) return;
    int a = A[n];

    float h[64];
    #pragma unroll
    for (int j = 0; j < 64; j++) h[j] = s_b1[j];
    #pragma unroll 1
    for (int k = 0; k < 16; k++) {
        float ek = s_emb[a * 16 + k];
        #pragma unroll
        for (int j = 0; j < 64; j++) h[j] += ek * s_w1[k * 64 + j];
    }
    #pragma unroll
    for (int j = 0; j < 64; j++) h[j] = silu_f(h[j]);

    #pragma unroll 1
    for (int u = 0; u < MUL; u++) {
        float acc = s_b2[u];
        #pragma unroll
        for (int k = 0; k < 64; k++) acc += h[k] * s_w2[k * MUL + u];
        Ai[n * MUL + u] = acc;
    }
}

// ---------------- CSR build ----------------
__global__ void count_kernel(const int* __restrict__ edst, int* __restrict__ count, int E) {
    int e = blockIdx.x * blockDim.x + threadIdx.x;
    if (e < E) atomicAdd(&count[edst[e]], 1);
}

__global__ void scan_kernel(const int* __restrict__ count, int* __restrict__ off, int N) {
    __shared__ int sums[1024];
    int L = N + 1;
    int chunk = (L + 1023) / 1024;
    int t = threadIdx.x;
    int lo = t * chunk;
    int hi = lo + chunk; if (hi > L) hi = L;
    int local = 0;
    for (int i = lo; i < hi; i++) local += (i < N) ? count[i] : 0;
    sums[t] = local;
    __syncthreads();
    for (int s = 1; s < 1024; s <<= 1) {
        int v = (t >= s) ? sums[t - s] : 0;
        __syncthreads();
        sums[t] += v;
        __syncthreads();
    }
    int run = (t == 0) ? 0 : sums[t - 1];
    for (int i = lo; i < hi; i++) {
        off[i] = run;
        run += (i < N) ? count[i] : 0;
    }
}

__global__ void fill_kernel(const int* __restrict__ edst, const int* __restrict__ off,
                            int* __restrict__ cursor, int* __restrict__ list, int E) {
    int e = blockIdx.x * blockDim.x + threadIdx.x;
    if (e >= E) return;
    int d = edst[e];
    int p = atomicAdd(&cursor[d], 1);
    list[off[d] + p] = e;
}

// ---------------- phase A: per-edge compute -> 56-float record (staged write) ----------------
__global__ void __launch_bounds__(256) edge_compute_kernel(
        const float* __restrict__ pos, const int* __restrict__ batch,
        const int* __restrict__ esrc, const int* __restrict__ edst,
        const float* __restrict__ shifts, const float* __restrict__ cell,
        const float* __restrict__ fw1, const float* __restrict__ fb1,
        const float* __restrict__ fw2, const float* __restrict__ fb2,
        const float* __restrict__ fw3, const float* __restrict__ fb3,
        const float* __restrict__ tpw,
        const float* __restrict__ Ai,
        float* __restrict__ ebuf, int E) {
    __shared__ float s_w1[16 * 64];    // [k][j] j-consecutive
    __shared__ float s_w2t[64 * 64];   // transposed: [j][k] k-consecutive
    __shared__ float s_w3[64 * 3];
    __shared__ float s_b1[64];
    __shared__ float s_b2[64];
    __shared__ float s_b3[4];
    __shared__ float s_tpw[3 * 1024];  // [l][u][v][w] w-consecutive
    __shared__ float s_stage[64 * SPAD];

    for (int i = threadIdx.x; i < 1024; i += 256) s_w1[i] = fw1[i];
    for (int i = threadIdx.x; i < 4096; i += 256) {
        int j = i >> 6, k = i & 63;
        s_w2t[i] = fw2[k * 64 + j];    // transpose at load
    }
    for (int i = threadIdx.x; i < 64; i += 256) { s_b1[i] = fb1[i]; s_b2[i] = fb2[i]; }
    for (int i = threadIdx.x; i < 192; i += 256) {
        int j = i / 3, c = i - 3 * j;
        int cc = (c == 0) ? 0 : ((c == 1) ? 3 : 9);
        s_w3[i] = fw3[j * 15 + cc];
    }
    if (threadIdx.x < 3) {
        int cc = (threadIdx.x == 0) ? 0 : ((threadIdx.x == 1) ? 3 : 9);
        s_b3[threadIdx.x] = fb3[cc];
    }
    for (int i = threadIdx.x; i < 3 * 1024; i += 256) {
        int l = i >> 10, r = i & 1023;
        int p = (l == 0) ? 0 : ((l == 1) ? 3 : 9);
        s_tpw[i] = tpw[p * 1024 + r];
    }
    __syncthreads();

    int e = blockIdx.x * 256 + threadIdx.x;
    bool active = (e < E);

    float4 t[3][4];
    #pragma unroll
    for (int l = 0; l < 3; l++)
        #pragma unroll
        for (int w4 = 0; w4 < 4; w4++) t[l][w4] = make_float4(0.f, 0.f, 0.f, 0.f);
    float y10 = 0.f, y11 = 0.f, y12 = 0.f, y20 = 0.f, y21 = 0.f, y22 = 0.f, y23 = 0.f, y24 = 0.f;

    if (active) {
        int s = esrc[e], d = edst[e];
        int g = batch[s];
        float sh0 = shifts[e * 3 + 0], sh1 = shifts[e * 3 + 1], sh2 = shifts[e * 3 + 2];
        const float* cg = cell + g * 9;
        float sv0 = sh0 * cg[0] + sh1 * cg[3] + sh2 * cg[6];
        float sv1 = sh0 * cg[1] + sh1 * cg[4] + sh2 * cg[7];
        float sv2 = sh0 * cg[2] + sh1 * cg[5] + sh2 * cg[8];
        float vx = pos[d * 3 + 0] - pos[s * 3 + 0] + sv0;
        float vy = pos[d * 3 + 1] - pos[s * 3 + 1] + sv1;
        float vz = pos[d * 3 + 2] - pos[s * 3 + 2] + sv2;
        float len = sqrtf(vx * vx + vy * vy + vz * vz);
        float inv = 1.0f / fmaxf(len, 1e-8f);
        float nx = vx * inv, ny = vy * inv, nz = vz * inv;

        // ---- radial MLP, float4 LDS reads ----
        float r = len * (17.0f / 5.0f);
        float4 h4[16];
        const float4* b1_4 = (const float4*)s_b1;
        #pragma unroll
        for (int j4 = 0; j4 < 16; j4++) h4[j4] = b1_4[j4];
        #pragma unroll 1
        for (int k = 0; k < 16; k++) {
            float dk = r - (float)(k + 1);
            float ek = __expf(-dk * dk) * (4.0f / 1.12f);
            const float4* w1r = (const float4*)(s_w1 + (k << 6));
            #pragma unroll
            for (int j4 = 0; j4 < 16; j4++) {
                float4 w = w1r[j4];
                h4[j4].x += ek * w.x; h4[j4].y += ek * w.y;
                h4[j4].z += ek * w.z; h4[j4].w += ek * w.w;
            }
        }
        #pragma unroll
        for (int j4 = 0; j4 < 16; j4++) {
            h4[j4].x = silu_f(h4[j4].x); h4[j4].y = silu_f(h4[j4].y);
            h4[j4].z = silu_f(h4[j4].z); h4[j4].w = silu_f(h4[j4].w);
        }

        float g0 = s_b3[0], g1 = s_b3[1], g2 = s_b3[2];
        #pragma unroll 2
        for (int j = 0; j < 64; j++) {
            const float4* w2r = (const float4*)(s_w2t + (j << 6));
            float a = s_b2[j];
            #pragma unroll
            for (int k4 = 0; k4 < 16; k4++) {
                float4 w = w2r[k4];
                a += h4[k4].x * w.x + h4[k4].y * w.y + h4[k4].z * w.z + h4[k4].w * w.w;
            }
            a = silu_f(a);
            g0 += a * s_w3[j * 3 + 0];
            g1 += a * s_w3[j * 3 + 1];
            g2 += a * s_w3[j * 3 + 2];
        }
        g0 *= 0.125f; g1 *= 0.125f; g2 *= 0.125f;   // PATH_NORM

        // ---- bilinear, float4 over w; u rolled (As re-read via L1), v/l/w4 unrolled ----
        const float4* Ad4p = (const float4*)(Ai + d * MUL);
        float4 Ad0 = Ad4p[0], Ad1 = Ad4p[1];
        const float* As = Ai + s * MUL;
        const float4* tp4 = (const float4*)s_tpw;
        #pragma unroll 1
        for (int u = 0; u < 8; u++) {
            float asu = As[u];
            int ub = u << 5;   // u*128 floats = u*32 float4
            #pragma unroll
            for (int v = 0; v < 8; v++) {
                float adv = (v < 4) ? ((v == 0) ? Ad0.x : (v == 1) ? Ad0.y : (v == 2) ? Ad0.z : Ad0.w)
                                    : ((v == 4) ? Ad1.x : (v == 5) ? Ad1.y : (v == 6) ? Ad1.z : Ad1.w);
                float pv = asu * adv;
                int o4 = ub + (v << 2);  // float4 offset of (u,v) within a path
                #pragma unroll
                for (int l = 0; l < 3; l++) {
                    #pragma unroll
                    for (int w4 = 0; w4 < 4; w4++) {
                        float4 w = tp4[(l << 8) + o4 + w4];
                        t[l][w4].x += pv * w.x; t[l][w4].y += pv * w.y;
                        t[l][w4].z += pv * w.z; t[l][w4].w += pv * w.w;
                    }
                }
            }
        }
        #pragma unroll
        for (int w4 = 0; w4 < 4; w4++) {
            t[0][w4].x *= g0; t[0][w4].y *= g0; t[0][w4].z *= g0; t[0][w4].w *= g0;
            t[1][w4].x *= g1; t[1][w4].y *= g1; t[1][w4].z *= g1; t[1][w4].w *= g1;
            t[2][w4].x *= g2; t[2][w4].y *= g2; t[2][w4].z *= g2; t[2][w4].w *= g2;
        }

        const float s3 = 1.7320508075688772f;
        const float s15 = 3.872983346207417f;
        const float s5h = 1.118033988749895f;
        y10 = s3 * nx; y11 = s3 * ny; y12 = s3 * nz;
        y20 = s15 * nx * ny; y21 = s15 * ny * nz; y22 = s5h * (3.f * nz * nz - 1.f);
        y23 = s15 * nx * nz; y24 = 0.5f * s15 * (nx * nx - ny * ny);
    }

    // ---- staged coalesced write: 4 wave-rounds through one 64-record LDS buffer ----
    int wave = threadIdx.x >> 6, lane = threadIdx.x & 63;
    float4* st4 = (float4*)s_stage;
    float4* eb4 = (float4*)ebuf;
    #pragma unroll 1
    for (int rnd = 0; rnd < 4; rnd++) {
        __syncthreads();
        if (wave == rnd && active) {
            float4* dst = (float4*)(s_stage + lane * SPAD);
            dst[0] = t[0][0]; dst[1] = t[0][1]; dst[2]  = t[0][2]; dst[3]  = t[0][3];
            dst[4] = t[1][0]; dst[5] = t[1][1]; dst[6]  = t[1][2]; dst[7]  = t[1][3];
            dst[8] = t[2][0]; dst[9] = t[2][1]; dst[10] = t[2][2]; dst[11] = t[2][3];
            dst[12] = make_float4(y10, y11, y12, y20);
            dst[13] = make_float4(y21, y22, y23, y24);
        }
        __syncthreads();
        long long base_e = (long long)blockIdx.x * 256 + rnd * 64;
        #pragma unroll
        for (int k = 0; k < 4; k++) {
            int idx = threadIdx.x + k * 256;
            if (idx < 64 * 14) {
                int le = idx / 14, comp = idx - le * 14;
                long long ge = base_e + le;
                if (ge < E) eb4[ge * 14 + comp] = st4[le * (SPAD / 4) + comp];
            }
        }
    }
}

// ---------------- phase B: gather, 4 nodes per 576-thread block ----------------
__global__ void __launch_bounds__(576) gather_kernel(
        const float* __restrict__ ebuf, const int* __restrict__ off,
        const int* __restrict__ list, float* __restrict__ out, int N) {
    int t = threadIdx.x;
    int ln = t / 144;
    int c = t - ln * 144;
    int n = blockIdx.x * 4 + ln;
    if (n >= N) return;
    int b = off[n], eN = off[n + 1];
    float val = 0.f;
    if (c < 16) {
        for (int j = b; j < eN; j++) {
            size_t base = (size_t)list[j] * EREC;
            val += ebuf[base + c];
        }
    } else if (c < 64) {
        int rr = c - 16, w = rr / 3, i = rr - 3 * w;
        for (int j = b; j < eN; j++) {
            size_t base = (size_t)list[j] * EREC;
            val += ebuf[base + 16 + w] * ebuf[base + 48 + i];
        }
    } else {
        int rr = c - 64, w = rr / 5, i = rr - 5 * w;
        for (int j = b; j < eN; j++) {
            size_t base = (size_t)list[j] * EREC;
            val += ebuf[base + 32 + w] * ebuf[base + 51 + i];
        }
    }
    float dg = (float)(eN - b);
    out[(size_t)n * NCOL + c] = val / fmaxf(dg, 1.0f);
}

// ================= fallback (small ws): atomic path =================
__global__ void __launch_bounds__(256) edge_atomic_kernel(
        const float* __restrict__ pos, const int* __restrict__ batch,
        const int* __restrict__ esrc, const int* __restrict__ edst,
        const float* __restrict__ shifts, const float* __restrict__ cell,
        const float* __restrict__ fw1, const float* __restrict__ fb1,
        const float* __restrict__ fw2, const float* __restrict__ fb2,
        const float* __restrict__ fw3, const float* __restrict__ fb3,
        const float* __restrict__ tpw,
        const float* __restrict__ Ai,
        float* __restrict__ out, float* __restrict__ deg, int E) {
    __shared__ float s_w1[16 * 64];
    __shared__ float s_w2[64 * 64];
    __shared__ float s_w3[64 * 3];
    __shared__ float s_b1[64];
    __shared__ float s_b2[64];
    __shared__ float s_b3[3];
    __shared__ float s_tpw[3 * 1024];
    for (int i = threadIdx.x; i < 1024; i += blockDim.x) s_w1[i] = fw1[i];
    for (int i = threadIdx.x; i < 4096; i += blockDim.x) s_w2[i] = fw2[i];
    for (int i = threadIdx.x; i < 64; i += blockDim.x) { s_b1[i] = fb1[i]; s_b2[i] = fb2[i]; }
    for (int i = threadIdx.x; i < 192; i += blockDim.x) {
        int j = i / 3, c = i - 3 * j;
        int cc = (c == 0) ? 0 : ((c == 1) ? 3 : 9);
        s_w3[i] = fw3[j * 15 + cc];
    }
    if (threadIdx.x < 3) {
        int cc = (threadIdx.x == 0) ? 0 : ((threadIdx.x == 1) ? 3 : 9);
        s_b3[threadIdx.x] = fb3[cc];
    }
    for (int i = threadIdx.x; i < 3 * 1024; i += blockDim.x) {
        int l = i >> 10, r = i & 1023;
        int p = (l == 0) ? 0 : ((l == 1) ? 3 : 9);
        s_tpw[i] = tpw[p * 1024 + r];
    }
    __syncthreads();
    int e = blockIdx.x * blockDim.x + threadIdx.x;
    if (e >= E) return;
    int s = esrc[e], d = edst[e];
    int g = batch[s];
    float sh0 = shifts[e * 3 + 0], sh1 = shifts[e * 3 + 1], sh2 = shifts[e * 3 + 2];
    const float* cg = cell + g * 9;
    float sv0 = sh0 * cg[0] + sh1 * cg[3] + sh2 * cg[6];
    float sv1 = sh0 * cg[1] + sh1 * cg[4] + sh2 * cg[7];
    float sv2 = sh0 * cg[2] + sh1 * cg[5] + sh2 * cg[8];
    float vx = pos[d * 3 + 0] - pos[s * 3 + 0] + sv0;
    float vy = pos[d * 3 + 1] - pos[s * 3 + 1] + sv1;
    float vz = pos[d * 3 + 2] - pos[s * 3 + 2] + sv2;
    float len = sqrtf(vx * vx + vy * vy + vz * vz);
    float inv = 1.0f / fmaxf(len, 1e-8f);
    float nx = vx * inv, ny = vy * inv, nz = vz * inv;
    float r = len * (17.0f / 5.0f);
    float h[64];
    #pragma unroll
    for (int j = 0; j < 64; j++) h[j] = s_b1[j];
    #pragma unroll 1
    for (int k = 0; k < 16; k++) {
        float dk = r - (float)(k + 1);
        float ek = __expf(-dk * dk) * (4.0f / 1.12f);
        #pragma unroll
        for (int j = 0; j < 64; j++) h[j] += ek * s_w1[k * 64 + j];
    }
    #pragma unroll
    for (int j = 0; j < 64; j++) h[j] = silu_f(h[j]);
    float g0 = s_b3[0], g1 = s_b3[1], g2 = s_b3[2];
    #pragma unroll 2
    for (int j = 0; j < 64; j++) {
        float a = s_b2[j];
        #pragma unroll
        for (int k = 0; k < 64; k++) a += h[k] * s_w2[k * 64 + j];
        a = silu_f(a);
        g0 += a * s_w3[j * 3 + 0];
        g1 += a * s_w3[j * 3 + 1];
        g2 += a * s_w3[j * 3 + 2];
    }
    g0 *= 0.125f; g1 *= 0.125f; g2 *= 0.125f;
    float t0[16], t1[16], t2[16];
    #pragma unroll
    for (int w = 0; w < 16; w++) { t0[w] = 0.f; t1[w] = 0.f; t2[w] = 0.f; }
    int s8 = s * MUL, d8 = d * MUL;
    float Ad[8];
    #pragma unroll
    for (int v = 0; v < 8; v++) Ad[v] = Ai[d8 + v];
    #pragma unroll 1
    for (int u = 0; u < 8; u++) {
        float asu = Ai[s8 + u];
        int offp = u * 128;
        #pragma unroll
        for (int v = 0; v < 8; v++) {
            float p = asu * Ad[v];
            int o2 = offp + v * 16;
            #pragma unroll
            for (int w = 0; w < 16; w++) {
                t0[w] += p * s_tpw[o2 + w];
                t1[w] += p * s_tpw[1024 + o2 + w];
                t2[w] += p * s_tpw[2048 + o2 + w];
            }
        }
    }
    #pragma unroll
    for (int w = 0; w < 16; w++) { t0[w] *= g0; t1[w] *= g1; t2[w] *= g2; }
    const float s3 = 1.7320508075688772f;
    const float s15 = 3.872983346207417f;
    const float s5h = 1.118033988749895f;
    float y1_[3] = { s3 * nx, s3 * ny, s3 * nz };
    float y2_[5] = { s15 * nx * ny, s15 * ny * nz, s5h * (3.f * nz * nz - 1.f),
                     s15 * nx * nz, 0.5f * s15 * (nx * nx - ny * ny) };
    float* o = out + (size_t)d * NCOL;
    #pragma unroll
    for (int w = 0; w < 16; w++) atomicAdd(o + w, t0[w]);
    #pragma unroll
    for (int w = 0; w < 16; w++)
        #pragma unroll
        for (int i = 0; i < 3; i++) atomicAdd(o + 16 + w * 3 + i, t1[w] * y1_[i]);
    #pragma unroll
    for (int w = 0; w < 16; w++)
        #pragma unroll
        for (int i = 0; i < 5; i++) atomicAdd(o + 64 + w * 5 + i, t2[w] * y2_[i]);
    atomicAdd(deg + d, 1.0f);
}

__global__ void finalize_kernel(float* __restrict__ out, const float* __restrict__ deg, int total) {
    int idx = blockIdx.x * blockDim.x + threadIdx.x;
    if (idx >= total) return;
    int n = idx / NCOL;
    out[idx] = out[idx] / fmaxf(deg[n], 1.0f);
}

extern "C" void kernel_launch(void* const* d_in, const int* in_sizes, int n_in,
                              void* d_out, int out_size, void* d_ws, size_t ws_size,
                              hipStream_t stream) {
    const float* pos    = (const float*)d_in[0];
    const int*   A      = (const int*)d_in[1];
    const int*   batch  = (const int*)d_in[2];
    const int*   esrc   = (const int*)d_in[3];
    const int*   edst   = (const int*)d_in[4];
    const float* shifts = (const float*)d_in[5];
    const float* cellp  = (const float*)d_in[6];
    const float* embt   = (const float*)d_in[7];
    const float* aw1    = (const float*)d_in[8];
    const float* ab1    = (const float*)d_in[9];
    const float* aw2    = (const float*)d_in[10];
    const float* ab2    = (const float*)d_in[11];
    const float* fw1    = (const float*)d_in[12];
    const float* fb1    = (const float*)d_in[13];
    const float* fw2    = (const float*)d_in[14];
    const float* fb2    = (const float*)d_in[15];
    const float* fw3    = (const float*)d_in[16];
    const float* fb3    = (const float*)d_in[17];
    const float* tpw    = (const float*)d_in[18];

    int N = in_sizes[1];
    int E = in_sizes[3];
    float* out = (float*)d_out;

    // ws layout (CSR path): Ai[N*8] | count[N] | cursor[N] | off[N+1] | list[E] | ebuf[E*56] (256B-aligned)
    size_t need = (size_t)N * 32 + (size_t)N * 4 * 2 + (size_t)(N + 1) * 4
                + (size_t)E * 4 + (size_t)E * EREC * 4 + 512;

    if (ws_size >= need) {
        float* Ai    = (float*)d_ws;
        int*   count = (int*)(Ai + (size_t)N * MUL);
        int*   cursor= count + N;
        int*   off   = cursor + N;
        int*   list  = off + (N + 1);
        float* ebuf  = (float*)(((uintptr_t)(list + E) + 255) & ~(uintptr_t)255);

        hipMemsetAsync(count, 0, (size_t)N * 2 * sizeof(int), stream);  // count + cursor

        node_mlp_kernel<<<(N + 255) / 256, 256, 0, stream>>>(A, embt, aw1, ab1, aw2, ab2, Ai, N);
        count_kernel<<<(E + 255) / 256, 256, 0, stream>>>(edst, count, E);
        scan_kernel<<<1, 1024, 0, stream>>>(count, off, N);
        fill_kernel<<<(E + 255) / 256, 256, 0, stream>>>(edst, off, cursor, list, E);

        edge_compute_kernel<<<(E + 255) / 256, 256, 0, stream>>>(
            pos, batch, esrc, edst, shifts, cellp,
            fw1, fb1, fw2, fb2, fw3, fb3, tpw, Ai, ebuf, E);

        gather_kernel<<<(N + 3) / 4, 576, 0, stream>>>(ebuf, off, list, out, N);
    } else {
        float* Ai  = (float*)d_ws;
        float* deg = Ai + (size_t)N * MUL;
        hipMemsetAsync(out, 0, (size_t)out_size * sizeof(float), stream);
        hipMemsetAsync(deg, 0, (size_t)N * sizeof(float), stream);
        node_mlp_kernel<<<(N + 255) / 256, 256, 0, stream>>>(A, embt, aw1, ab1, aw2, ab2, Ai, N);
        edge_atomic_kernel<<<(E + 255) / 256, 256, 0, stream>>>(
            pos, batch, esrc, edst, shifts, cellp,
            fw1, fb1, fw2, fb2, fw3, fb3, tpw, Ai, out, deg, E);
        int total = N * NCOL;
        finalize_kernel<<<(total + 255) / 256, 256, 0, stream>>>(out, deg, total);
    }
}

// Round 10
// 808.901 us; speedup vs baseline: 1.2348x; 1.2348x over previous
//
#include <hip/hip_runtime.h>
#include <hip/hip_bf16.h>
#include <math.h>

#define MUL 8
#define NCOL 144   // 16*(1+3+5)
#define EREC 56    // per-slot record: t0[16] t1[16] t2[16] y1[3] y2[5]
#define SPAD 60    // LDS stage stride in floats

__device__ __forceinline__ float silu_f(float x) { return x / (1.0f + __expf(-x)); }

// ---------------- node MLP -> Ai[N][8] ----------------
__global__ void node_mlp_kernel(const int* __restrict__ A,
                                const float* __restrict__ emb_table,
                                const float* __restrict__ w1,
                                const float* __restrict__ b1,
                                const float* __restrict__ w2,
                                const float* __restrict__ b2,
                                float* __restrict__ Ai, int N) {
    __shared__ float s_w1[16 * 64];
    __shared__ float s_w2[64 * MUL];
    __shared__ float s_b1[64];
    __shared__ float s_b2[MUL];
    __shared__ float s_emb[10 * 16];
    for (int i = threadIdx.x; i < 16 * 64; i += blockDim.x) s_w1[i] = w1[i];
    for (int i = threadIdx.x; i < 64 * MUL; i += blockDim.x) s_w2[i] = w2[i];
    for (int i = threadIdx.x; i < 64; i += blockDim.x) s_b1[i] = b1[i];
    for (int i = threadIdx.x; i < MUL; i += blockDim.x) s_b2[i] = b2[i];
    for (int i = threadIdx.x; i < 160; i += blockDim.x) s_emb[i] = emb_table[i];
    __syncthreads();

    int n = blockIdx.x * blockDim.x + threadIdx.x;
    if (n >= N) return;
    int a = A[n];

    float h[64];
    #pragma unroll
    for (int j = 0; j < 64; j++) h[j] = s_b1[j];
    #pragma unroll 1
    for (int k = 0; k < 16; k++) {
        float ek = s_emb[a * 16 + k];
        #pragma unroll
        for (int j = 0; j < 64; j++) h[j] += ek * s_w1[k * 64 + j];
    }
    #pragma unroll
    for (int j = 0; j < 64; j++) h[j] = silu_f(h[j]);

    #pragma unroll 1
    for (int u = 0; u < MUL; u++) {
        float acc = s_b2[u];
        #pragma unroll
        for (int k = 0; k < 64; k++) acc += h[k] * s_w2[k * MUL + u];
        Ai[n * MUL + u] = acc;
    }
}

// ---------------- CSR build ----------------
__global__ void count_kernel(const int* __restrict__ edst, int* __restrict__ count, int E) {
    int e = blockIdx.x * blockDim.x + threadIdx.x;
    if (e < E) atomicAdd(&count[edst[e]], 1);
}

__global__ void scan_kernel(const int* __restrict__ count, int* __restrict__ off, int N) {
    __shared__ int sums[1024];
    int L = N + 1;
    int chunk = (L + 1023) / 1024;
    int t = threadIdx.x;
    int lo = t * chunk;
    int hi = lo + chunk; if (hi > L) hi = L;
    int local = 0;
    for (int i = lo; i < hi; i++) local += (i < N) ? count[i] : 0;
    sums[t] = local;
    __syncthreads();
    for (int s = 1; s < 1024; s <<= 1) {
        int v = (t >= s) ? sums[t - s] : 0;
        __syncthreads();
        sums[t] += v;
        __syncthreads();
    }
    int run = (t == 0) ? 0 : sums[t - 1];
    for (int i = lo; i < hi; i++) {
        off[i] = run;
        run += (i < N) ? count[i] : 0;
    }
}

__global__ void fill_kernel(const int* __restrict__ edst, const int* __restrict__ off,
                            int* __restrict__ cursor, int* __restrict__ list, int E) {
    int e = blockIdx.x * blockDim.x + threadIdx.x;
    if (e >= E) return;
    int d = edst[e];
    int p = atomicAdd(&cursor[d], 1);
    list[off[d] + p] = e;   // slot -> edge id
}

// ---------------- phase A: per-CSR-slot compute -> contiguous 56-float record ----------------
__global__ void __launch_bounds__(256) edge_compute_kernel(
        const float* __restrict__ pos, const int* __restrict__ batch,
        const int* __restrict__ esrc, const int* __restrict__ edst,
        const float* __restrict__ shifts, const float* __restrict__ cell,
        const float* __restrict__ fw1, const float* __restrict__ fb1,
        const float* __restrict__ fw2, const float* __restrict__ fb2,
        const float* __restrict__ fw3, const float* __restrict__ fb3,
        const float* __restrict__ tpw,
        const float* __restrict__ Ai, const int* __restrict__ list,
        float* __restrict__ ebuf, int E) {
    __shared__ float s_w1[16 * 64];    // [k][j] j-consecutive
    __shared__ float s_w2t[64 * 64];   // transposed: [j][k] k-consecutive
    __shared__ float s_w3[64 * 3];
    __shared__ float s_b1[64];
    __shared__ float s_b2[64];
    __shared__ float s_b3[4];
    __shared__ float s_tpw[3 * 1024];  // [l][u][v][w] w-consecutive
    __shared__ float s_stage[64 * SPAD];

    for (int i = threadIdx.x; i < 1024; i += 256) s_w1[i] = fw1[i];
    for (int i = threadIdx.x; i < 4096; i += 256) {
        int j = i >> 6, k = i & 63;
        s_w2t[i] = fw2[k * 64 + j];
    }
    for (int i = threadIdx.x; i < 64; i += 256) { s_b1[i] = fb1[i]; s_b2[i] = fb2[i]; }
    for (int i = threadIdx.x; i < 192; i += 256) {
        int j = i / 3, c = i - 3 * j;
        int cc = (c == 0) ? 0 : ((c == 1) ? 3 : 9);
        s_w3[i] = fw3[j * 15 + cc];
    }
    if (threadIdx.x < 3) {
        int cc = (threadIdx.x == 0) ? 0 : ((threadIdx.x == 1) ? 3 : 9);
        s_b3[threadIdx.x] = fb3[cc];
    }
    for (int i = threadIdx.x; i < 3 * 1024; i += 256) {
        int l = i >> 10, r = i & 1023;
        int p = (l == 0) ? 0 : ((l == 1) ? 3 : 9);
        s_tpw[i] = tpw[p * 1024 + r];
    }
    __syncthreads();

    int slot = blockIdx.x * 256 + threadIdx.x;
    bool active = (slot < E);

    float4 t[3][4];
    #pragma unroll
    for (int l = 0; l < 3; l++)
        #pragma unroll
        for (int w4 = 0; w4 < 4; w4++) t[l][w4] = make_float4(0.f, 0.f, 0.f, 0.f);
    float y10 = 0.f, y11 = 0.f, y12 = 0.f, y20 = 0.f, y21 = 0.f, y22 = 0.f, y23 = 0.f, y24 = 0.f;

    if (active) {
        int e = list[slot];
        int s = esrc[e], d = edst[e];
        int g = batch[s];
        float sh0 = shifts[e * 3 + 0], sh1 = shifts[e * 3 + 1], sh2 = shifts[e * 3 + 2];
        const float* cg = cell + g * 9;
        float sv0 = sh0 * cg[0] + sh1 * cg[3] + sh2 * cg[6];
        float sv1 = sh0 * cg[1] + sh1 * cg[4] + sh2 * cg[7];
        float sv2 = sh0 * cg[2] + sh1 * cg[5] + sh2 * cg[8];
        float vx = pos[d * 3 + 0] - pos[s * 3 + 0] + sv0;
        float vy = pos[d * 3 + 1] - pos[s * 3 + 1] + sv1;
        float vz = pos[d * 3 + 2] - pos[s * 3 + 2] + sv2;
        float len = sqrtf(vx * vx + vy * vy + vz * vz);
        float inv = 1.0f / fmaxf(len, 1e-8f);
        float nx = vx * inv, ny = vy * inv, nz = vz * inv;

        // ---- radial MLP ----
        float r = len * (17.0f / 5.0f);
        float4 h4[16];
        const float4* b1_4 = (const float4*)s_b1;
        #pragma unroll
        for (int j4 = 0; j4 < 16; j4++) h4[j4] = b1_4[j4];
        #pragma unroll 1
        for (int k = 0; k < 16; k++) {
            float dk = r - (float)(k + 1);
            float ek = __expf(-dk * dk) * (4.0f / 1.12f);
            const float4* w1r = (const float4*)(s_w1 + (k << 6));
            #pragma unroll
            for (int j4 = 0; j4 < 16; j4++) {
                float4 w = w1r[j4];
                h4[j4].x += ek * w.x; h4[j4].y += ek * w.y;
                h4[j4].z += ek * w.z; h4[j4].w += ek * w.w;
            }
        }
        #pragma unroll
        for (int j4 = 0; j4 < 16; j4++) {
            h4[j4].x = silu_f(h4[j4].x); h4[j4].y = silu_f(h4[j4].y);
            h4[j4].z = silu_f(h4[j4].z); h4[j4].w = silu_f(h4[j4].w);
        }

        float g0 = s_b3[0], g1 = s_b3[1], g2 = s_b3[2];
        #pragma unroll 2
        for (int j = 0; j < 64; j++) {
            const float4* w2r = (const float4*)(s_w2t + (j << 6));
            float a = s_b2[j];
            #pragma unroll
            for (int k4 = 0; k4 < 16; k4++) {
                float4 w = w2r[k4];
                a += h4[k4].x * w.x + h4[k4].y * w.y + h4[k4].z * w.z + h4[k4].w * w.w;
            }
            a = silu_f(a);
            g0 += a * s_w3[j * 3 + 0];
            g1 += a * s_w3[j * 3 + 1];
            g2 += a * s_w3[j * 3 + 2];
        }
        g0 *= 0.125f; g1 *= 0.125f; g2 *= 0.125f;   // PATH_NORM

        // ---- bilinear ----
        const float4* Ad4p = (const float4*)(Ai + d * MUL);
        float4 Ad0 = Ad4p[0], Ad1 = Ad4p[1];
        const float* As = Ai + s * MUL;
        const float4* tp4 = (const float4*)s_tpw;
        #pragma unroll 1
        for (int u = 0; u < 8; u++) {
            float asu = As[u];
            int ub = u << 5;
            #pragma unroll
            for (int v = 0; v < 8; v++) {
                float adv = (v < 4) ? ((v == 0) ? Ad0.x : (v == 1) ? Ad0.y : (v == 2) ? Ad0.z : Ad0.w)
                                    : ((v == 4) ? Ad1.x : (v == 5) ? Ad1.y : (v == 6) ? Ad1.z : Ad1.w);
                float pv = asu * adv;
                int o4 = ub + (v << 2);
                #pragma unroll
                for (int l = 0; l < 3; l++) {
                    #pragma unroll
                    for (int w4 = 0; w4 < 4; w4++) {
                        float4 w = tp4[(l << 8) + o4 + w4];
                        t[l][w4].x += pv * w.x; t[l][w4].y += pv * w.y;
                        t[l][w4].z += pv * w.z; t[l][w4].w += pv * w.w;
                    }
                }
            }
        }
        #pragma unroll
        for (int w4 = 0; w4 < 4; w4++) {
            t[0][w4].x *= g0; t[0][w4].y *= g0; t[0][w4].z *= g0; t[0][w4].w *= g0;
            t[1][w4].x *= g1; t[1][w4].y *= g1; t[1][w4].z *= g1; t[1][w4].w *= g1;
            t[2][w4].x *= g2; t[2][w4].y *= g2; t[2][w4].z *= g2; t[2][w4].w *= g2;
        }

        const float s3 = 1.7320508075688772f;
        const float s15 = 3.872983346207417f;
        const float s5h = 1.118033988749895f;
        y10 = s3 * nx; y11 = s3 * ny; y12 = s3 * nz;
        y20 = s15 * nx * ny; y21 = s15 * ny * nz; y22 = s5h * (3.f * nz * nz - 1.f);
        y23 = s15 * nx * nz; y24 = 0.5f * s15 * (nx * nx - ny * ny);
    }

    // ---- staged coalesced write (records land at CSR slot -> contiguous per node) ----
    int wave = threadIdx.x >> 6, lane = threadIdx.x & 63;
    float4* st4 = (float4*)s_stage;
    float4* eb4 = (float4*)ebuf;
    #pragma unroll 1
    for (int rnd = 0; rnd < 4; rnd++) {
        __syncthreads();
        if (wave == rnd && active) {
            float4* dst = (float4*)(s_stage + lane * SPAD);
            dst[0] = t[0][0]; dst[1] = t[0][1]; dst[2]  = t[0][2]; dst[3]  = t[0][3];
            dst[4] = t[1][0]; dst[5] = t[1][1]; dst[6]  = t[1][2]; dst[7]  = t[1][3];
            dst[8] = t[2][0]; dst[9] = t[2][1]; dst[10] = t[2][2]; dst[11] = t[2][3];
            dst[12] = make_float4(y10, y11, y12, y20);
            dst[13] = make_float4(y21, y22, y23, y24);
        }
        __syncthreads();
        long long base_s = (long long)blockIdx.x * 256 + rnd * 64;
        #pragma unroll
        for (int k = 0; k < 4; k++) {
            int idx = threadIdx.x + k * 256;
            if (idx < 64 * 14) {
                int le = idx / 14, comp = idx - le * 14;
                long long gs = base_s + le;
                if (gs < E) eb4[gs * 14 + comp] = st4[le * (SPAD / 4) + comp];
            }
        }
    }
}

// ---------------- phase B: streaming gather, 1 node / 192 threads ----------------
__global__ void __launch_bounds__(192) gather_kernel(
        const float* __restrict__ ebuf, const int* __restrict__ off,
        float* __restrict__ out, int N) {
    int n = blockIdx.x;
    int c = threadIdx.x;
    if (c >= NCOL) return;
    int b = off[n], eN = off[n + 1];
    float val = 0.f;
    if (c < 16) {
        for (int j = b; j < eN; j++) val += ebuf[(size_t)j * EREC + c];
    } else if (c < 64) {
        int rr = c - 16, w = rr / 3, i = rr - 3 * w;
        for (int j = b; j < eN; j++) {
            const float* rec = ebuf + (size_t)j * EREC;
            val += rec[16 + w] * rec[48 + i];
        }
    } else {
        int rr = c - 64, w = rr / 5, i = rr - 5 * w;
        for (int j = b; j < eN; j++) {
            const float* rec = ebuf + (size_t)j * EREC;
            val += rec[32 + w] * rec[51 + i];
        }
    }
    float dg = (float)(eN - b);
    out[(size_t)n * NCOL + c] = val / fmaxf(dg, 1.0f);
}

// ================= fallback (small ws): atomic path =================
__global__ void __launch_bounds__(256) edge_atomic_kernel(
        const float* __restrict__ pos, const int* __restrict__ batch,
        const int* __restrict__ esrc, const int* __restrict__ edst,
        const float* __restrict__ shifts, const float* __restrict__ cell,
        const float* __restrict__ fw1, const float* __restrict__ fb1,
        const float* __restrict__ fw2, const float* __restrict__ fb2,
        const float* __restrict__ fw3, const float* __restrict__ fb3,
        const float* __restrict__ tpw,
        const float* __restrict__ Ai,
        float* __restrict__ out, float* __restrict__ deg, int E) {
    __shared__ float s_w1[16 * 64];
    __shared__ float s_w2[64 * 64];
    __shared__ float s_w3[64 * 3];
    __shared__ float s_b1[64];
    __shared__ float s_b2[64];
    __shared__ float s_b3[3];
    __shared__ float s_tpw[3 * 1024];
    for (int i = threadIdx.x; i < 1024; i += blockDim.x) s_w1[i] = fw1[i];
    for (int i = threadIdx.x; i < 4096; i += blockDim.x) s_w2[i] = fw2[i];
    for (int i = threadIdx.x; i < 64; i += blockDim.x) { s_b1[i] = fb1[i]; s_b2[i] = fb2[i]; }
    for (int i = threadIdx.x; i < 192; i += blockDim.x) {
        int j = i / 3, c = i - 3 * j;
        int cc = (c == 0) ? 0 : ((c == 1) ? 3 : 9);
        s_w3[i] = fw3[j * 15 + cc];
    }
    if (threadIdx.x < 3) {
        int cc = (threadIdx.x == 0) ? 0 : ((threadIdx.x == 1) ? 3 : 9);
        s_b3[threadIdx.x] = fb3[cc];
    }
    for (int i = threadIdx.x; i < 3 * 1024; i += blockDim.x) {
        int l = i >> 10, r = i & 1023;
        int p = (l == 0) ? 0 : ((l == 1) ? 3 : 9);
        s_tpw[i] = tpw[p * 1024 + r];
    }
    __syncthreads();
    int e = blockIdx.x * blockDim.x + threadIdx.x;
    if (e >= E) return;
    int s = esrc[e], d = edst[e];
    int g = batch[s];
    float sh0 = shifts[e * 3 + 0], sh1 = shifts[e * 3 + 1], sh2 = shifts[e * 3 + 2];
    const float* cg = cell + g * 9;
    float sv0 = sh0 * cg[0] + sh1 * cg[3] + sh2 * cg[6];
    float sv1 = sh0 * cg[1] + sh1 * cg[4] + sh2 * cg[7];
    float sv2 = sh0 * cg[2] + sh1 * cg[5] + sh2 * cg[8];
    float vx = pos[d * 3 + 0] - pos[s * 3 + 0] + sv0;
    float vy = pos[d * 3 + 1] - pos[s * 3 + 1] + sv1;
    float vz = pos[d * 3 + 2] - pos[s * 3 + 2] + sv2;
    float len = sqrtf(vx * vx + vy * vy + vz * vz);
    float inv = 1.0f / fmaxf(len, 1e-8f);
    float nx = vx * inv, ny = vy * inv, nz = vz * inv;
    float r = len * (17.0f / 5.0f);
    float h[64];
    #pragma unroll
    for (int j = 0; j < 64; j++) h[j] = s_b1[j];
    #pragma unroll 1
    for (int k = 0; k < 16; k++) {
        float dk = r - (float)(k + 1);
        float ek = __expf(-dk * dk) * (4.0f / 1.12f);
        #pragma unroll
        for (int j = 0; j < 64; j++) h[j] += ek * s_w1[k * 64 + j];
    }
    #pragma unroll
    for (int j = 0; j < 64; j++) h[j] = silu_f(h[j]);
    float g0 = s_b3[0], g1 = s_b3[1], g2 = s_b3[2];
    #pragma unroll 2
    for (int j = 0; j < 64; j++) {
        float a = s_b2[j];
        #pragma unroll
        for (int k = 0; k < 64; k++) a += h[k] * s_w2[k * 64 + j];
        a = silu_f(a);
        g0 += a * s_w3[j * 3 + 0];
        g1 += a * s_w3[j * 3 + 1];
        g2 += a * s_w3[j * 3 + 2];
    }
    g0 *= 0.125f; g1 *= 0.125f; g2 *= 0.125f;
    float t0[16], t1[16], t2[16];
    #pragma unroll
    for (int w = 0; w < 16; w++) { t0[w] = 0.f; t1[w] = 0.f; t2[w] = 0.f; }
    int s8 = s * MUL, d8 = d * MUL;
    float Ad[8];
    #pragma unroll
    for (int v = 0; v < 8; v++) Ad[v] = Ai[d8 + v];
    #pragma unroll 1
    for (int u = 0; u < 8; u++) {
        float asu = Ai[s8 + u];
        int offp = u * 128;
        #pragma unroll
        for (int v = 0; v < 8; v++) {
            float p = asu * Ad[v];
            int o2 = offp + v * 16;
            #pragma unroll
            for (int w = 0; w < 16; w++) {
                t0[w] += p * s_tpw[o2 + w];
                t1[w] += p * s_tpw[1024 + o2 + w];
                t2[w] += p * s_tpw[2048 + o2 + w];
            }
        }
    }
    #pragma unroll
    for (int w = 0; w < 16; w++) { t0[w] *= g0; t1[w] *= g1; t2[w] *= g2; }
    const float s3 = 1.7320508075688772f;
    const float s15 = 3.872983346207417f;
    const float s5h = 1.118033988749895f;
    float y1_[3] = { s3 * nx, s3 * ny, s3 * nz };
    float y2_[5] = { s15 * nx * ny, s15 * ny * nz, s5h * (3.f * nz * nz - 1.f),
                     s15 * nx * nz, 0.5f * s15 * (nx * nx - ny * ny) };
    float* o = out + (size_t)d * NCOL;
    #pragma unroll
    for (int w = 0; w < 16; w++) atomicAdd(o + w, t0[w]);
    #pragma unroll
    for (int w = 0; w < 16; w++)
        #pragma unroll
        for (int i = 0; i < 3; i++) atomicAdd(o + 16 + w * 3 + i, t1[w] * y1_[i]);
    #pragma unroll
    for (int w = 0; w < 16; w++)
        #pragma unroll
        for (int i = 0; i < 5; i++) atomicAdd(o + 64 + w * 5 + i, t2[w] * y2_[i]);
    atomicAdd(deg + d, 1.0f);
}

__global__ void finalize_kernel(float* __restrict__ out, const float* __restrict__ deg, int total) {
    int idx = blockIdx.x * blockDim.x + threadIdx.x;
    if (idx >= total) return;
    int n = idx / NCOL;
    out[idx] = out[idx] / fmaxf(deg[n], 1.0f);
}

extern "C" void kernel_launch(void* const* d_in, const int* in_sizes, int n_in,
                              void* d_out, int out_size, void* d_ws, size_t ws_size,
                              hipStream_t stream) {
    const float* pos    = (const float*)d_in[0];
    const int*   A      = (const int*)d_in[1];
    const int*   batch  = (const int*)d_in[2];
    const int*   esrc   = (const int*)d_in[3];
    const int*   edst   = (const int*)d_in[4];
    const float* shifts = (const float*)d_in[5];
    const float* cellp  = (const float*)d_in[6];
    const float* embt   = (const float*)d_in[7];
    const float* aw1    = (const float*)d_in[8];
    const float* ab1    = (const float*)d_in[9];
    const float* aw2    = (const float*)d_in[10];
    const float* ab2    = (const float*)d_in[11];
    const float* fw1    = (const float*)d_in[12];
    const float* fb1    = (const float*)d_in[13];
    const float* fw2    = (const float*)d_in[14];
    const float* fb2    = (const float*)d_in[15];
    const float* fw3    = (const float*)d_in[16];
    const float* fb3    = (const float*)d_in[17];
    const float* tpw    = (const float*)d_in[18];

    int N = in_sizes[1];
    int E = in_sizes[3];
    float* out = (float*)d_out;

    // ws layout (CSR path): Ai[N*8] | count[N] | cursor[N] | off[N+1] | list[E] | ebuf[E*56]
    size_t need = (size_t)N * 32 + (size_t)N * 4 * 2 + (size_t)(N + 1) * 4
                + (size_t)E * 4 + (size_t)E * EREC * 4 + 512;

    if (ws_size >= need) {
        float* Ai    = (float*)d_ws;
        int*   count = (int*)(Ai + (size_t)N * MUL);
        int*   cursor= count + N;
        int*   off   = cursor + N;
        int*   list  = off + (N + 1);
        float* ebuf  = (float*)(((uintptr_t)(list + E) + 255) & ~(uintptr_t)255);

        hipMemsetAsync(count, 0, (size_t)N * 2 * sizeof(int), stream);  // count + cursor

        node_mlp_kernel<<<(N + 255) / 256, 256, 0, stream>>>(A, embt, aw1, ab1, aw2, ab2, Ai, N);
        count_kernel<<<(E + 255) / 256, 256, 0, stream>>>(edst, count, E);
        scan_kernel<<<1, 1024, 0, stream>>>(count, off, N);
        fill_kernel<<<(E + 255) / 256, 256, 0, stream>>>(edst, off, cursor, list, E);

        edge_compute_kernel<<<(E + 255) / 256, 256, 0, stream>>>(
            pos, batch, esrc, edst, shifts, cellp,
            fw1, fb1, fw2, fb2, fw3, fb3, tpw, Ai, list, ebuf, E);

        gather_kernel<<<N, 192, 0, stream>>>(ebuf, off, out, N);
    } else {
        float* Ai  = (float*)d_ws;
        float* deg = Ai + (size_t)N * MUL;
        hipMemsetAsync(out, 0, (size_t)out_size * sizeof(float), stream);
        hipMemsetAsync(deg, 0, (size_t)N * sizeof(float), stream);
        node_mlp_kernel<<<(N + 255) / 256, 256, 0, stream>>>(A, embt, aw1, ab1, aw2, ab2, Ai, N);
        edge_atomic_kernel<<<(E + 255) / 256, 256, 0, stream>>>(
            pos, batch, esrc, edst, shifts, cellp,
            fw1, fb1, fw2, fb2, fw3, fb3, tpw, Ai, out, deg, E);
        int total = N * NCOL;
        finalize_kernel<<<(total + 255) / 256, 256, 0, stream>>>(out, deg, total);
    }
}